// Round 3
// baseline (230.809 us; speedup 1.0000x reference)
//
#include <hip/hip_runtime.h>
#include <climits>

#define N_ 16384
#define H_ 256
#define W_ 704
#define HW_ (H_*W_)
#define NC_ (N_*16)
#define EPS_ 1e-3f
#define HDR_ 512

typedef unsigned long long ull;

// ---- workspace layout (float units) ----
// ints [0..5]: sum_y, sum_x, min_y, max_y, min_x, max_x ; [6]=scanA arrive, [7]=attn arrive
// [136..151] kA [152..167] kC [168..183] fcA [184..199] fcC
// [200..215] tA [216..231] tC [232..247] fA [248..263] fC
// [264] cy [265] cx [266] inv_mx_y [267] inv_mx_x
// arrays at HDR_: pts_lin(0) pos_lin(1) gath(2) t_lin(3) off(4,5) attn(6) neigh(7) f_lin(8) val(9..)
#define VAL_   (HDR_ + 9*NC_)
#define KNNI_  (VAL_ + HW_*16)
#define PARTF_ (KNNI_ + 378256)
#define PK_    (PARTF_ + 8192)
#define PFC_   (PARTF_ + 16384)
#define PT_    (PARTF_ + 24576)

#define CAP_ 6144

__device__ __forceinline__ float wsum64(float v){
#pragma unroll
  for (int o = 32; o > 0; o >>= 1) v += __shfl_down(v, o);
  return v;
}

#define LOAD16(dst, src) { const float4* _s=(const float4*)(src); float4 _a=_s[0],_b=_s[1],_c=_s[2],_d=_s[3]; \
  dst[0]=_a.x;dst[1]=_a.y;dst[2]=_a.z;dst[3]=_a.w; dst[4]=_b.x;dst[5]=_b.y;dst[6]=_b.z;dst[7]=_b.w; \
  dst[8]=_c.x;dst[9]=_c.y;dst[10]=_c.z;dst[11]=_c.w; dst[12]=_d.x;dst[13]=_d.y;dst[14]=_d.z;dst[15]=_d.w; }

#define STORE16(dst, src) { float4* _d=(float4*)(dst); \
  _d[0]=make_float4(src[0],src[1],src[2],src[3]); _d[1]=make_float4(src[4],src[5],src[6],src[7]); \
  _d[2]=make_float4(src[8],src[9],src[10],src[11]); _d[3]=make_float4(src[12],src[13],src[14],src[15]); }

__device__ __forceinline__ void knn_insert(ull* arr, ull key){
  if (key < arr[8]){
    int q = 8;
    while (q > 0 && arr[q-1] > key){ arr[q] = arr[q-1]; --q; }
    arr[q] = key;
  }
}

__device__ __forceinline__ void scan_rows_global(const int* __restrict__ cellst,
                                                 const unsigned* __restrict__ psort,
                                                 int y, int x, int s,
                                                 int y0, int y1, int x0, int x1, ull* arr){
  for (int yy=y0+s; yy<=y1; yy+=4){
    int rowb = yy*W_;
    int st = cellst[rowb + x0];
    int e  = cellst[rowb + x1 + 1];
    int dy = y-yy, dy2 = dy*dy;
    for (int p=st; p<e; ++p){
      unsigned u = psort[p];
      int px = (int)((u>>14)&1023);
      int dx = x-px;
      knn_insert(arr, ((ull)(unsigned)(dy2+dx*dx) << 14) | (ull)(u & 16383u));
    }
  }
}

// reduce 256x32 partials -> BN affine coefs (one block of 256 threads)
__device__ __forceinline__ void red_body(const float* __restrict__ g, const float* __restrict__ bta,
                                         const float* __restrict__ part, float* __restrict__ coef,
                                         float* __restrict__ red){
  int t = threadIdx.x, slot = t & 31, chunk = t >> 5;
  float acc = 0.f;
  for (int bb=chunk*32; bb<chunk*32+32; ++bb) acc += part[bb*32 + slot];
  red[t] = acc;
  __syncthreads();
  if (chunk == 0){
    float v = red[slot];
#pragma unroll
    for (int k2=1;k2<8;++k2) v += red[k2*32+slot];
    red[slot] = v;
  }
  __syncthreads();
  if (t < 16){
    float mu  = red[t]    * (1.f/N_);
    float var = red[16+t] * (1.f/N_) - mu*mu;
    float a = g[t] / sqrtf(var + EPS_);
    coef[t]    = a;
    coef[16+t] = bta[t] - mu*a;
  }
  __syncthreads();
}

// ============ L1: zero counts + header || pts_lin+partK || gather || val projection ============
// blocks: [0,176) zero, 176 header, [177,241) pts_lin, [241,1265) gather, [1265,1969) valproj
__global__ __launch_bounds__(256) void k1(const float* __restrict__ pf,
                                          const float* __restrict__ imf,
                                          const int* __restrict__ grid,
                                          const float* __restrict__ Wk, const float* __restrict__ bk,
                                          const float* __restrict__ Wval, const float* __restrict__ bval,
                                          float* __restrict__ ws){
  __shared__ float sA[256], sB[16];
  const int t = threadIdx.x, b = blockIdx.x;
  const bool ldsK = (b >= 177 && b < 241);
  const bool ldsV = (b >= 1265);
  if (ldsK){ sA[t] = Wk[t];   if (t < 16) sB[t] = bk[t]; }
  if (ldsV){ sA[t] = Wval[t]; if (t < 16) sB[t] = bval[t]; }
  if (ldsK || ldsV) __syncthreads();

  if (b < 176){
    int4* c4 = (int4*)(ws + KNNI_);
    c4[b*256 + t] = make_int4(0,0,0,0);
  } else if (b == 176){
    if (t == 0){
      int* ih = (int*)ws;
      ih[0]=0; ih[1]=0; ih[2]=INT_MAX; ih[3]=INT_MIN; ih[4]=INT_MAX; ih[5]=INT_MIN;
      ih[6]=0; ih[7]=0;
    }
  } else if (ldsK){
    const int i = (b-177)*256 + t;
    float p[16]; LOAD16(p, pf + i*16);
    float ok[16];
#pragma unroll
    for (int c=0;c<16;++c) ok[c] = sB[c];
#pragma unroll
    for (int j=0;j<16;++j){ float v = p[j];
#pragma unroll
      for (int c=0;c<16;++c) ok[c] += v*sA[j*16+c];
    }
    STORE16(ws + HDR_ + i*16, ok);
    float* partK = ws + PK_;
    const int grp = i >> 6;
#pragma unroll
    for (int c=0;c<16;++c){
      float a = wsum64(ok[c]); float q2 = wsum64(ok[c]*ok[c]);
      if ((t&63)==0){ partK[grp*32+c]=a; partK[grp*32+16+c]=q2; }
    }
  } else if (b < 1265){
    const int idx = (b-241)*256 + t;     // 0..262143
    const int i = idx >> 4, c = idx & 15;
    int2 g = ((const int2*)grid)[i];
    ws[HDR_ + 2*NC_ + idx] = imf[c*HW_ + g.x*W_ + g.y];
  } else {
    const int pix = (b-1265)*256 + t;    // 0..180223
    float a[16];
#pragma unroll
    for (int ci=0;ci<16;++ci) a[ci] = imf[ci*HW_ + pix];
    float o[16];
#pragma unroll
    for (int c=0;c<16;++c) o[c] = sB[c];
#pragma unroll
    for (int ci=0;ci<16;++ci){ float v=a[ci];
#pragma unroll
      for (int c=0;c<16;++c) o[c] += v*sA[ci*16+c];
    }
    STORE16(ws + VAL_ + pix*16, o);
  }
}

// ============ L2: gridcnt + header stats (blocks 0..63) || red(K) (block 64) ============
__global__ __launch_bounds__(256) void k2(const int* __restrict__ grid,
                                          const float* __restrict__ gk, const float* __restrict__ betak,
                                          float* __restrict__ ws){
  const int t = threadIdx.x, b = blockIdx.x;
  if (b < 64){
    int i = b*256 + t;
    int2 p = ((const int2*)grid)[i];
    int* counts = (int*)(ws + KNNI_);
    atomicAdd(&counts[p.x*W_ + p.y], 1);
    int sy=p.x, sx=p.y, mny=p.x, mxy=p.x, mnx=p.y, mxx=p.y;
#pragma unroll
    for (int o=32;o>0;o>>=1){
      sy += __shfl_down(sy,o); sx += __shfl_down(sx,o);
      mny = min(mny,__shfl_down(mny,o)); mxy = max(mxy,__shfl_down(mxy,o));
      mnx = min(mnx,__shfl_down(mnx,o)); mxx = max(mxx,__shfl_down(mxx,o));
    }
    __shared__ int sh[24];
    int w = t >> 6;
    if ((t & 63) == 0){
      sh[w]=sy; sh[4+w]=sx; sh[8+w]=mny; sh[12+w]=mxy; sh[16+w]=mnx; sh[20+w]=mxx;
    }
    __syncthreads();
    if (t == 0){
      int a0=sh[0]+sh[1]+sh[2]+sh[3];
      int a1=sh[4]+sh[5]+sh[6]+sh[7];
      int a2=min(min(sh[8],sh[9]),min(sh[10],sh[11]));
      int a3=max(max(sh[12],sh[13]),max(sh[14],sh[15]));
      int a4=min(min(sh[16],sh[17]),min(sh[18],sh[19]));
      int a5=max(max(sh[20],sh[21]),max(sh[22],sh[23]));
      int* ih = (int*)ws;
      atomicAdd(&ih[0],a0); atomicAdd(&ih[1],a1);
      atomicMin(&ih[2],a2); atomicMax(&ih[3],a3);
      atomicMin(&ih[4],a4); atomicMax(&ih[5],a5);
    }
  } else {
    __shared__ float red[256];
    red_body(gk, betak, ws + PK_, ws + 136, red);
  }
}

// ============ L3: scanA (blocks 0..703; last block does 704-scan + center) || t_lin (704..767) ============
__global__ __launch_bounds__(256) void k3(const float* __restrict__ Wt, const float* __restrict__ bt,
                                          float* __restrict__ ws){
  const int t = threadIdx.x, b = blockIdx.x;
  int* ih = (int*)ws;
  int* counts = (int*)(ws + KNNI_);
  int* bsum   = counts + 360464;
  int* boffp  = bsum + 704;
  if (b < 704){
    __shared__ int w4[4];
    __shared__ int sWin;
    int v = counts[b*256 + t];
#pragma unroll
    for (int o=32;o>0;o>>=1) v += __shfl_down(v,o);
    if ((t&63)==0) w4[t>>6] = v;
    __syncthreads();
    if (t == 0){
      bsum[b] = w4[0]+w4[1]+w4[2]+w4[3];
      __threadfence();
      int old = atomicAdd(&ih[6], 1);
      sWin = (old == 703) ? 1 : 0;
    }
    __syncthreads();
    if (sWin){
      if (t == 0) __threadfence();   // acquire: all 704 bsum writes visible
      __syncthreads();
      if (t == 0){
        float cy = (float)ih[0] / (float)N_;
        float cx = (float)ih[1] / (float)N_;
        float my = fmaxf((float)ih[3]-cy, cy-(float)ih[2]);
        float mx = fmaxf((float)ih[5]-cx, cx-(float)ih[4]);
        if (my == 0.f) my = 1.f;
        if (mx == 0.f) mx = 1.f;
        ws[264]=cy; ws[265]=cx; ws[266]=1.f/my; ws[267]=1.f/mx;
      }
      __shared__ int sWsum[4];
      __shared__ int sCarry;
      int lane = t & 63, wv = t >> 6;
      if (t==0) sCarry = 0;
      __syncthreads();
      for (int c=0;c<3;++c){
        int idx = c*256 + t;
        int v0 = (idx < 704) ? bsum[idx] : 0;
        int vv = v0;
#pragma unroll
        for (int o=1;o<64;o<<=1){ int xx=__shfl_up(vv,o); if (lane>=o) vv+=xx; }
        if (lane==63) sWsum[wv]=vv;
        __syncthreads();
        int add = sCarry;
        for (int w2=0;w2<wv;++w2) add += sWsum[w2];
        if (idx < 704) boffp[idx] = add + vv - v0;
        __syncthreads();
        if (t==255) sCarry = add + vv;
        __syncthreads();
      }
    }
  } else {
    __shared__ float sWt[256];
    sWt[t] = Wt[t];
    __syncthreads();
    const int i = (b-704)*256 + t;
    float kA[16], kC[16];
    LOAD16(kA, ws+136); LOAD16(kC, ws+152);
    float pl[16]; LOAD16(pl, ws + HDR_ + i*16);
    float pts[16];
#pragma unroll
    for (int c=0;c<16;++c) pts[c] = pl[c]*kA[c] + kC[c];
    float tv[16];
#pragma unroll
    for (int c=0;c<16;++c) tv[c] = bt[c];
#pragma unroll
    for (int j=0;j<16;++j){ float v = pts[j];
#pragma unroll
      for (int c=0;c<16;++c) tv[c] += v*sWt[j*16+c];
    }
    STORE16(ws + HDR_ + 3*NC_ + i*16, tv);
    float* partT = ws + PT_;
    const int grp = i >> 6;
#pragma unroll
    for (int c=0;c<16;++c){
      float a = wsum64(tv[c]); float q2 = wsum64(tv[c]*tv[c]);
      if ((t&63)==0){ partT[grp*32+c]=a; partT[grp*32+16+c]=q2; }
    }
  }
}

// ============ L4: scanC (0..703) || pos_lin+partFC (704..767) || red(T) (768) ============
__global__ __launch_bounds__(256) void k4(const int* __restrict__ grid,
                                          const float* __restrict__ Wfc, const float* __restrict__ bfc,
                                          const float* __restrict__ gt, const float* __restrict__ betat,
                                          float* __restrict__ ws){
  const int t = threadIdx.x, b = blockIdx.x;
  int* counts = (int*)(ws + KNNI_);
  int* cellst = counts + 180224;
  int* bsum   = counts + 360464;
  int* boffp  = bsum + 704;
  if (b < 704){
    __shared__ int sWsum[4];
    int lane = t & 63, wv = t >> 6;
    int i = b*256 + t;
    int v0 = counts[i], v = v0;
#pragma unroll
    for (int o=1;o<64;o<<=1){ int xx=__shfl_up(v,o); if (lane>=o) v+=xx; }
    if (lane==63) sWsum[wv]=v;
    __syncthreads();
    int add = boffp[b];
    for (int w2=0;w2<wv;++w2) add += sWsum[w2];
    int start = add + v - v0;
    cellst[i] = start;
    counts[i] = start;          // becomes the scatter cursor
    if (i == 0) cellst[HW_] = N_;
  } else if (b < 768){
    const int i = (b-704)*256 + t;
    float cy=ws[264], cx=ws[265], imy=ws[266], imx=ws[267];
    int2 g = ((const int2*)grid)[i];
    float ry = ((float)g.x - cy)*imy, rx = ((float)g.y - cx)*imx;
    float op[16];
#pragma unroll
    for (int c=0;c<16;++c) op[c] = ry*Wfc[c] + rx*Wfc[16+c] + bfc[c];
    STORE16(ws + HDR_ + NC_ + i*16, op);
    float* partFC = ws + PFC_;
    const int grp = i >> 6;
#pragma unroll
    for (int c=0;c<16;++c){
      float a = wsum64(op[c]); float q2 = wsum64(op[c]*op[c]);
      if ((t&63)==0){ partFC[grp*32+c]=a; partFC[grp*32+16+c]=q2; }
    }
  } else {
    __shared__ float red[256];
    red_body(gt, betat, ws + PT_, ws + 200, red);
  }
}

// ============ L5: scatter (0..63) || red(FC) (64) ============
__global__ __launch_bounds__(256) void k5(const int* __restrict__ grid,
                                          const float* __restrict__ gfc, const float* __restrict__ betafc,
                                          float* __restrict__ ws){
  const int t = threadIdx.x, b = blockIdx.x;
  if (b < 64){
    int i = b*256 + t;
    int2 g = ((const int2*)grid)[i];
    int* counts = (int*)(ws + KNNI_);
    unsigned* psort = (unsigned*)(counts + 180224 + 180240 + 704 + 704);
    int pos = atomicAdd(&counts[g.x*W_ + g.y], 1);
    psort[pos] = ((unsigned)g.x<<24) | ((unsigned)g.y<<14) | (unsigned)i;
  } else {
    __shared__ float red[256];
    red_body(gfc, betafc, ws + PFC_, ws + 168, red);
  }
}

// ============ L6: KNN + neighbor mean (0..255) || off/attn projection + softmax (256..319) ============
__global__ __launch_bounds__(256) void k6(const float* __restrict__ WoffW, const float* __restrict__ boffW,
                                          const float* __restrict__ Wattn, const float* __restrict__ battn,
                                          float* __restrict__ ws){
  const int t = threadIdx.x, b = blockIdx.x;
  if (b < 256){
    const int* cellst = (const int*)(ws + KNNI_) + 180224;
    const unsigned* psort = (const unsigned*)((const int*)(ws + KNNI_) + 180224 + 180240 + 704 + 704);
    __shared__ unsigned sBand[CAP_];
    __shared__ int sRowBase[80];
    __shared__ int sMn, sMx;
    int lane = t & 63;
    int s = t & 3, pl = t >> 2;
    int gid = b*64 + pl;
    unsigned me = psort[gid];
    int y = (int)(me>>24), x = (int)((me>>14)&1023), i = (int)(me&16383);
    if (t==0){ sMn = INT_MAX; sMx = -1; }
    __syncthreads();
    if (s==0){ atomicMin(&sMn, y); atomicMax(&sMx, y); }
    __syncthreads();
    int ya = max(sMn-16,0), yb = min(sMx+16,H_-1);
    int nr = yb-ya+1;
    int p0 = cellst[ya*W_], p1 = cellst[(yb+1)*W_];
    int count = p1-p0;
    bool fb = (count > CAP_) || (nr > 78);
    if (!fb){
      for (int j=t; j<count; j+=256) sBand[j] = psort[p0+j];
      for (int j=t; j<=nr; j+=256) sRowBase[j] = cellst[(ya+j)*W_] - p0;
    }
    __syncthreads();
    int r = 8;
    { int y0=max(y-8,0),y1=min(y+8,H_-1),x0=max(x-8,0),x1=min(x+8,W_-1);
      if ((y1-y0+1)*(x1-x0+1) < 224) r = 16; }
    ull arr[9];
#pragma unroll
    for (int q=0;q<9;++q) arr[q] = ~0ull;
    {
      int y0=max(y-r,0),y1=min(y+r,H_-1),x0=max(x-r,0),x1=min(x+r,W_-1);
      if (!fb){
        for (int yy=y0+s; yy<=y1; yy+=4){
          int j = yy-ya;
          int bb = sRowBase[j], e = sRowBase[j+1];
          int lo=bb, hi=e;
          while (lo<hi){ int mid=(lo+hi)>>1; int xm=(int)((sBand[mid]>>14)&1023); if (xm<x0) lo=mid+1; else hi=mid; }
          int dy = y-yy, dy2 = dy*dy;
          for (int p=lo; p<e; ++p){
            unsigned u = sBand[p];
            int px = (int)((u>>14)&1023);
            if (px > x1) break;
            int dx = x-px;
            knn_insert(arr, ((ull)(unsigned)(dy2+dx*dx) << 14) | (ull)(u & 16383u));
          }
        }
      } else {
        scan_rows_global(cellst, psort, y, x, s, y0, y1, x0, x1, arr);
      }
    }
    ull m[9];
    bool done = false;
    {
      ull k[9];
#pragma unroll
      for (int q=0;q<9;++q) m[q] = ~0ull;
      int base = lane & ~3;
      for (int ss=0; ss<4; ++ss){
#pragma unroll
        for (int q=0;q<9;++q) k[q] = __shfl(arr[q], base+ss);
        for (int q2=0;q2<9;++q2){
          ull kk = k[q2];
          if (kk >= m[8]) break;
          int q = 8; while (q>0 && m[q-1]>kk){ m[q]=m[q-1]; --q; } m[q]=kk;
        }
      }
      int y0=max(y-r,0),y1=min(y+r,H_-1),x0=max(x-r,0),x1=min(x+r,W_-1);
      bool covered = (y0==0)&&(y1==H_-1)&&(x0==0)&&(x1==W_-1);
      bool ok2 = covered;
      if (!ok2 && m[8] != ~0ull){ int d9 = (int)(m[8]>>14); ok2 = d9 < (r+1)*(r+1); }
      done = ok2;
    }
    while (__ballot(!done)){
      if (!done){
        r <<= 1;
        int y0=max(y-r,0),y1=min(y+r,H_-1),x0=max(x-r,0),x1=min(x+r,W_-1);
#pragma unroll
        for (int q=0;q<9;++q) arr[q] = ~0ull;
        scan_rows_global(cellst, psort, y, x, s, y0, y1, x0, x1, arr);
      }
      ull k[9];
      bool doIns = !done;
      if (doIns){
#pragma unroll
        for (int q=0;q<9;++q) m[q] = ~0ull;
      }
      int base = lane & ~3;
      for (int ss=0; ss<4; ++ss){
#pragma unroll
        for (int q=0;q<9;++q) k[q] = __shfl(arr[q], base+ss);
        if (doIns){
          for (int q2=0;q2<9;++q2){
            ull kk = k[q2];
            if (kk >= m[8]) break;
            int q = 8; while (q>0 && m[q-1]>kk){ m[q]=m[q-1]; --q; } m[q]=kk;
          }
        }
      }
      if (!done){
        int y0=max(y-r,0),y1=min(y+r,H_-1),x0=max(x-r,0),x1=min(x+r,W_-1);
        bool covered = (y0==0)&&(y1==H_-1)&&(x0==0)&&(x1==W_-1);
        bool ok2 = covered;
        if (!ok2 && m[8] != ~0ull){ int d9 = (int)(m[8]>>14); ok2 = d9 < (r+1)*(r+1); }
        if (ok2) done = true;
      }
    }
    const float* gath = ws + HDR_ + 2*NC_;
    float4 acc = make_float4(0.f,0.f,0.f,0.f);
#pragma unroll
    for (int nb=1; nb<9; ++nb){
      int idx = (int)(m[nb] & 16383ull);
      const float4 g4 = *(const float4*)(gath + idx*16 + s*4);
      acc.x += g4.x; acc.y += g4.y; acc.z += g4.z; acc.w += g4.w;
    }
    float* neigh = ws + HDR_ + 7*NC_;
    *(float4*)(neigh + i*16 + s*4) =
        make_float4(acc.x*0.125f, acc.y*0.125f, acc.z*0.125f, acc.w*0.125f);
  } else {
    __shared__ float sWoff[512], sWattn[256];
    __shared__ float sboff[32], sbattn[16];
    sWoff[t] = WoffW[t]; sWoff[256+t] = WoffW[256+t];
    sWattn[t] = Wattn[t];
    if (t < 32) sboff[t] = boffW[t];
    if (t < 16) sbattn[t] = battn[t];
    __syncthreads();
    const int i = (b-256)*256 + t;
    float kA[16],kC[16],fA[16],fC[16];
    LOAD16(kA, ws+136); LOAD16(kC, ws+152); LOAD16(fA, ws+168); LOAD16(fC, ws+184);
    float pl[16], po[16];
    LOAD16(pl, ws + HDR_ + i*16);
    LOAD16(po, ws + HDR_ + NC_ + i*16);
    float q[16];
#pragma unroll
    for (int c=0;c<16;++c) q[c] = pl[c]*kA[c]+kC[c] + po[c]*fA[c]+fC[c];
    float ov[32];
#pragma unroll
    for (int o=0;o<32;++o) ov[o] = sboff[o];
#pragma unroll
    for (int j=0;j<16;++j){ float v=q[j];
#pragma unroll
      for (int o=0;o<32;++o) ov[o] += v*sWoff[j*32+o];
    }
    { float4* d=(float4*)(ws + HDR_ + 4*NC_ + i*32);
#pragma unroll
      for (int rr=0;rr<8;++rr) d[rr]=make_float4(ov[rr*4],ov[rr*4+1],ov[rr*4+2],ov[rr*4+3]);
    }
    float l[16];
#pragma unroll
    for (int c=0;c<16;++c) l[c] = sbattn[c];
#pragma unroll
    for (int j=0;j<16;++j){ float v=q[j];
#pragma unroll
      for (int c=0;c<16;++c) l[c] += v*sWattn[j*16+c];
    }
    float av[16];
#pragma unroll
    for (int h=0;h<4;++h){
      float m = fmaxf(fmaxf(l[h*4],l[h*4+1]),fmaxf(l[h*4+2],l[h*4+3]));
      float e0=expf(l[h*4]-m), e1=expf(l[h*4+1]-m), e2=expf(l[h*4+2]-m), e3=expf(l[h*4+3]-m);
      float inv = 1.f/(e0+e1+e2+e3);
      av[h*4]=e0*inv; av[h*4+1]=e1*inv; av[h*4+2]=e2*inv; av[h*4+3]=e3*inv;
    }
    STORE16(ws + HDR_ + 6*NC_ + i*16, av);
  }
}

// ============ L7: deformable attn + Wout + fuse matmul + f-stats; last block does red(F) ============
__global__ __launch_bounds__(256) void k7(
    const int* __restrict__ grid,
    const float* __restrict__ Wout, const float* __restrict__ bout,
    const float* __restrict__ Wf, const float* __restrict__ bf,
    const float* __restrict__ gf, const float* __restrict__ betaf,
    float* __restrict__ ws)
{
  __shared__ float sWout[256], sWf[512], sbout[16], sbf[16];
  __shared__ float sTl[1024], sNei[1024], sSamp[1024], sImg[1024];
  __shared__ float sPart[128];
  __shared__ float red[256];
  __shared__ int sWin;
  int t = threadIdx.x, b = blockIdx.x;
  int p = t >> 2, h = t & 3;
  int i = b*64 + p;
  sWout[t]=Wout[t]; sWf[t]=Wf[t]; sWf[t+256]=Wf[t+256];
  if (t<16){ sbout[t]=bout[t]; sbf[t]=bf[t]; }
  {
    const float4* tl4 = (const float4*)(ws + HDR_ + 3*NC_ + b*1024);
    const float4* nv4 = (const float4*)(ws + HDR_ + 7*NC_ + b*1024);
    float4 v = tl4[t];
    int c0 = (t*4) & 15;
    float a0=ws[200+c0],a1=ws[201+c0],a2=ws[202+c0],a3=ws[203+c0];
    float c0v=ws[216+c0],c1v=ws[217+c0],c2v=ws[218+c0],c3v=ws[219+c0];
    sTl[t*4]   = fmaxf(v.x*a0+c0v, 0.f);
    sTl[t*4+1] = fmaxf(v.y*a1+c1v, 0.f);
    sTl[t*4+2] = fmaxf(v.z*a2+c2v, 0.f);
    sTl[t*4+3] = fmaxf(v.w*a3+c3v, 0.f);
    float4 nv = nv4[t];
    sNei[t*4]=nv.x; sNei[t*4+1]=nv.y; sNei[t*4+2]=nv.z; sNei[t*4+3]=nv.w;
  }
  const float4* off4 = (const float4*)(ws + HDR_ + 4*NC_ + b*2048);
  float4 o0 = off4[t*2], o1 = off4[t*2+1];
  float4 aw = ((const float4*)(ws + HDR_ + 6*NC_ + b*1024))[t];
  int2 g = ((const int2*)grid)[i];
  float y = (float)g.x, x = (float)g.y;
  const float4* val4 = (const float4*)(ws + VAL_);
  float4 acc = make_float4(0.f,0.f,0.f,0.f);
  float offv[8] = {o0.x,o0.y,o0.z,o0.w,o1.x,o1.y,o1.z,o1.w};
  float avv[4]  = {aw.x,aw.y,aw.z,aw.w};
#define CORNER(yy,xx,wgt) do{ int _y=(yy),_x=(xx); \
    if ((unsigned)_y < (unsigned)H_ && (unsigned)_x < (unsigned)W_){ \
      float4 _v = val4[(_y*W_+_x)*4 + h]; float _w = a*(wgt); \
      acc.x += _w*_v.x; acc.y += _w*_v.y; acc.z += _w*_v.z; acc.w += _w*_v.w; } }while(0)
#pragma unroll
  for (int pt=0; pt<4; ++pt){
    float a  = avv[pt];
    float ly = y + offv[pt*2], lx = x + offv[pt*2+1];
    float fy = floorf(ly), fx = floorf(lx);
    float wy = ly - fy, wx = lx - fx;
    int y0 = (int)fy, x0 = (int)fx;
    CORNER(y0,   x0,   (1.f-wy)*(1.f-wx));
    CORNER(y0,   x0+1, (1.f-wy)*wx);
    CORNER(y0+1, x0,   wy*(1.f-wx));
    CORNER(y0+1, x0+1, wy*wx);
  }
#undef CORNER
  ((float4*)sSamp)[t] = acc;
  __syncthreads();
  float img[4];
#pragma unroll
  for (int k=0;k<4;++k){ int cc=h*4+k; img[k] = sbout[cc] + sNei[p*16+cc]; }
#pragma unroll
  for (int j=0;j<16;++j){
    float v = sSamp[p*16+j];
#pragma unroll
    for (int k=0;k<4;++k) img[k] += v*sWout[j*16 + h*4 + k];
  }
  ((float4*)sImg)[t] = make_float4(img[0],img[1],img[2],img[3]);
  __syncthreads();
  float fl[4];
#pragma unroll
  for (int k=0;k<4;++k) fl[k] = sbf[h*4+k];
#pragma unroll
  for (int j=0;j<16;++j){
    float v1 = sTl[p*16+j];
    float v2 = fmaxf(sImg[p*16+j], 0.f);
#pragma unroll
    for (int k=0;k<4;++k){
      fl[k] += v1*sWf[j*16 + h*4 + k];
      fl[k] += v2*sWf[(16+j)*16 + h*4 + k];
    }
  }
  float* f_lin = ws + HDR_ + 8*NC_;
  ((float4*)(f_lin + b*1024))[t] = make_float4(fl[0],fl[1],fl[2],fl[3]);
  float s0=fl[0],s1=fl[1],s2=fl[2],s3=fl[3];
  float q0=fl[0]*fl[0],q1=fl[1]*fl[1],q2=fl[2]*fl[2],q3=fl[3]*fl[3];
#pragma unroll
  for (int o=32;o>=4;o>>=1){
    s0+=__shfl_down(s0,o); s1+=__shfl_down(s1,o); s2+=__shfl_down(s2,o); s3+=__shfl_down(s3,o);
    q0+=__shfl_down(q0,o); q1+=__shfl_down(q1,o); q2+=__shfl_down(q2,o); q3+=__shfl_down(q3,o);
  }
  int wave = t >> 6, lane = t & 63;
  if (lane < 4){
    sPart[wave*32 + lane*4+0]=s0; sPart[wave*32 + lane*4+1]=s1;
    sPart[wave*32 + lane*4+2]=s2; sPart[wave*32 + lane*4+3]=s3;
    sPart[wave*32 + 16 + lane*4+0]=q0; sPart[wave*32 + 16 + lane*4+1]=q1;
    sPart[wave*32 + 16 + lane*4+2]=q2; sPart[wave*32 + 16 + lane*4+3]=q3;
  }
  __syncthreads();
  if (t < 32){
    float v = sPart[t]+sPart[32+t]+sPart[64+t]+sPart[96+t];
    (ws + PARTF_)[b*32 + t] = v;
  }
  // ---- last-block-wins red(F): writers fence, arrive, winner reduces ----
  __threadfence();
  __syncthreads();
  if (t == 0){
    int old = atomicAdd(&((int*)ws)[7], 1);
    sWin = (old == 255) ? 1 : 0;
  }
  __syncthreads();
  if (sWin){
    if (t == 0) __threadfence();   // acquire: all blocks' partF visible
    __syncthreads();
    red_body(gf, betaf, ws + PARTF_, ws + 232, red);
  }
}

// ============ L8: output ============
__global__ __launch_bounds__(256) void k8(const float* __restrict__ ws, float* __restrict__ out){
  const int gtid = blockIdx.x*256 + threadIdx.x;
  const int idx4 = gtid*4;
  float4 v = *(const float4*)(ws + HDR_ + 8*NC_ + idx4);
  const int c = idx4 & 15;
  float4 r;
  r.x = fmaxf(v.x*ws[232+c] + ws[248+c], 0.f);
  r.y = fmaxf(v.y*ws[233+c] + ws[249+c], 0.f);
  r.z = fmaxf(v.z*ws[234+c] + ws[250+c], 0.f);
  r.w = fmaxf(v.w*ws[235+c] + ws[251+c], 0.f);
  *(float4*)(out + idx4) = r;
}

extern "C" void kernel_launch(void* const* d_in, const int* in_sizes, int n_in,
                              void* d_out, int out_size, void* d_ws, size_t ws_size,
                              hipStream_t stream)
{
  (void)in_sizes; (void)n_in; (void)out_size; (void)ws_size;
  const float* pf    = (const float*)d_in[0];
  const float* imf   = (const float*)d_in[1];
  const int*   gridp = (const int*)d_in[2];
  const float* Wk   =(const float*)d_in[3],  *bk   =(const float*)d_in[4];
  const float* gk   =(const float*)d_in[5],  *betak=(const float*)d_in[6];
  const float* Wfc  =(const float*)d_in[7],  *bfc  =(const float*)d_in[8];
  const float* gfc  =(const float*)d_in[9],  *betafc=(const float*)d_in[10];
  const float* Wt   =(const float*)d_in[11], *bt   =(const float*)d_in[12];
  const float* gt   =(const float*)d_in[13], *betat=(const float*)d_in[14];
  const float* Woff =(const float*)d_in[15], *boff =(const float*)d_in[16];
  const float* Wattn=(const float*)d_in[17], *battn=(const float*)d_in[18];
  const float* Wval =(const float*)d_in[19], *bval =(const float*)d_in[20];
  const float* Wout =(const float*)d_in[21], *bout =(const float*)d_in[22];
  const float* Wf   =(const float*)d_in[23], *bf   =(const float*)d_in[24];
  const float* gf   =(const float*)d_in[25], *betaf=(const float*)d_in[26];
  float* ws  = (float*)d_ws;
  float* out = (float*)d_out;

  hipLaunchKernelGGL(k1, dim3(1969), dim3(256), 0, stream, pf, imf, gridp, Wk, bk, Wval, bval, ws);
  hipLaunchKernelGGL(k2, dim3(65),   dim3(256), 0, stream, gridp, gk, betak, ws);
  hipLaunchKernelGGL(k3, dim3(768),  dim3(256), 0, stream, Wt, bt, ws);
  hipLaunchKernelGGL(k4, dim3(769),  dim3(256), 0, stream, gridp, Wfc, bfc, gt, betat, ws);
  hipLaunchKernelGGL(k5, dim3(65),   dim3(256), 0, stream, gridp, gfc, betafc, ws);
  hipLaunchKernelGGL(k6, dim3(320),  dim3(256), 0, stream, Woff, boff, Wattn, battn, ws);
  hipLaunchKernelGGL(k7, dim3(256),  dim3(256), 0, stream, gridp, Wout, bout, Wf, bf, gf, betaf, ws);
  hipLaunchKernelGGL(k8, dim3(256),  dim3(256), 0, stream, ws, out);
}